// Round 2
// baseline (354.271 us; speedup 1.0000x reference)
//
#include <hip/hip_runtime.h>

// Epsilon-greedy action selection.
//   q_vals:       [BATCH, N_ACTIONS] f32
//   rand_u:       [BATCH] f32
//   rand_actions: [BATCH] i32
//   out:          [BATCH] i32 = rand_u < eps ? rand_actions : argmax(q_vals, axis=1)
//
// Strategy: persistent waves, 16 contiguous rows per wave, 2-deep software
// pipeline. Each 64-lane wave covers one 512-float row with two coalesced
// float4 loads (1 KiB per load instruction); the loads for row r+1 are issued
// BEFORE the dependent 12-shuffle argmax chain of row r, so memory stays in
// flight across the reduction. 2048 blocks x 256 threads = 8192 waves =
// 32 waves/CU (full occupancy). Strict '>' + lower-index tie-break matches
// jnp.argmax semantics.

#define N_ACTIONS 512
#define EPSILON 0.05f
#define ROWS_PER_WAVE 16
#define WAVES_PER_BLOCK 4
#define ROWS_PER_BLOCK (ROWS_PER_WAVE * WAVES_PER_BLOCK)

__global__ __launch_bounds__(256) void
SelectAction_64862596104471_kernel(const float* __restrict__ q_vals,
                                   const float* __restrict__ rand_u,
                                   const int* __restrict__ rand_actions,
                                   int* __restrict__ out,
                                   int batch) {
    const int lane = threadIdx.x & 63;
    const long long wave = (long long)blockIdx.x * WAVES_PER_BLOCK + (threadIdx.x >> 6);
    const long long row0 = wave * ROWS_PER_WAVE;
    if (row0 >= batch) return;

    long long rem = (long long)batch - row0;
    const int nrows = (rem < ROWS_PER_WAVE) ? (int)rem : ROWS_PER_WAVE;

    // 128 float4 per row.
    const float4* q = (const float4*)q_vals + row0 * (N_ACTIONS / 4);

    // Pipeline stage 0: loads for row row0.
    float4 a = q[lane];
    float4 b = q[lane + 64];

    for (int r = 0; r < nrows; ++r) {
        // Prefetch next row before the dependent shuffle chain below; these
        // loads are independent of (a, b) so the compiler schedules them
        // before the lgkmcnt waits of the reduction.
        float4 na = a, nb = b;
        if (r + 1 < nrows) {
            const float4* qn = q + (long long)(r + 1) * (N_ACTIONS / 4);
            na = qn[lane];
            nb = qn[lane + 64];
        }

        // Lane-local argmax in ascending element-index order; strict '>'
        // keeps the lowest index on ties (jnp.argmax semantics).
        float best = a.x;
        int bidx = 4 * lane;
        if (a.y > best) { best = a.y; bidx = 4 * lane + 1; }
        if (a.z > best) { best = a.z; bidx = 4 * lane + 2; }
        if (a.w > best) { best = a.w; bidx = 4 * lane + 3; }
        if (b.x > best) { best = b.x; bidx = 256 + 4 * lane; }
        if (b.y > best) { best = b.y; bidx = 256 + 4 * lane + 1; }
        if (b.z > best) { best = b.z; bidx = 256 + 4 * lane + 2; }
        if (b.w > best) { best = b.w; bidx = 256 + 4 * lane + 3; }

        // 64-lane butterfly: prefer higher value; on exact tie prefer the
        // lower element index.
        #pragma unroll
        for (int off = 32; off > 0; off >>= 1) {
            float ov = __shfl_xor(best, off, 64);
            int oi = __shfl_xor(bidx, off, 64);
            if (ov > best || (ov == best && oi < bidx)) {
                best = ov;
                bidx = oi;
            }
        }

        if (lane == 0) {
            const long long row = row0 + r;
            // 16 consecutive rows share a 64B line of rand_u / rand_actions:
            // one miss, 15 L1 hits.
            out[row] = (rand_u[row] < EPSILON) ? rand_actions[row] : bidx;
        }

        a = na;
        b = nb;
    }
}

extern "C" void kernel_launch(void* const* d_in, const int* in_sizes, int n_in,
                              void* d_out, int out_size, void* d_ws, size_t ws_size,
                              hipStream_t stream) {
    const float* q_vals = (const float*)d_in[0];
    const float* rand_u = (const float*)d_in[1];
    const int* rand_actions = (const int*)d_in[2];
    int* out = (int*)d_out;

    const int batch = in_sizes[1];  // rand_u element count == BATCH

    const int blocks = (batch + ROWS_PER_BLOCK - 1) / ROWS_PER_BLOCK;
    SelectAction_64862596104471_kernel<<<blocks, 256, 0, stream>>>(
        q_vals, rand_u, rand_actions, out, batch);
}